// Round 10
// baseline (160.239 us; speedup 1.0000x reference)
//
#include <hip/hip_runtime.h>
#include <hip/hip_bf16.h>
#include <cstdint>

#define B_   8
#define LQ_  512
#define LK_  512
#define D_   512
#define H_   128

typedef __attribute__((ext_vector_type(8))) short  short8;   // 8 bf16 in 4 VGPRs
typedef __attribute__((ext_vector_type(4))) float  float4v;

// Eq = e^{2x} = exp2(C*x), C = 2*log2(e). tanh(q+k) = 1 - 2/(1 + Eq*Ek) exactly.
#define TANH_C 2.8853900817779268f

__device__ __forceinline__ short bf16rne(float x) {
  uint32_t u = __float_as_uint(x);
  return (short)((u + 0x7fffu + ((u >> 16) & 1u)) >> 16);
}

__device__ __forceinline__ float4v splat4(float x) {
  return (float4v){x, x, x, x};
}

// ---------------------------------------------------------------------------
// Kernel 1: reorder Wq/Wk (bf16) into MFMA B-fragment order, plus bake
//   w2[h] = -2*wv[h]  and  W0 = sum_h wv[h]  into ws for the score kernel.
// ---------------------------------------------------------------------------
__global__ __launch_bounds__(256) void prep_kernel(
    const float* __restrict__ Wq, const float* __restrict__ Wk,
    const float* __restrict__ wv,
    short* __restrict__ WqF, short* __restrict__ WkF,
    float* __restrict__ w2, float* __restrict__ W0buf) {
  int g = blockIdx.x * 256 + threadIdx.x;   // 0 .. 16383
  if (blockIdx.x == 0) {
    int t = threadIdx.x;
    if (t < H_) w2[t] = -2.0f * wv[t];
    if (t == H_) {
      float s = 0.f;
      for (int h = 0; h < H_; ++h) s += wv[h];
      W0buf[0] = s;
    }
  }
  int m = g >> 13;                          // 0: Wq, 1: Wk
  int r = g & 8191;                         // fragment index
  int l  = r & 63;
  int kb = (r >> 6) & 15;
  int nt = r >> 10;
  int col = nt * 16 + (l & 15);
  int k0  = kb * 32 + ((l >> 4) << 3);
  const float* W = m ? Wk : Wq;
  short8 f;
#pragma unroll
  for (int j = 0; j < 8; ++j) f[j] = bf16rne(W[(k0 + j) * H_ + col]);
  ((short8*)(m ? WkF : WqF))[r] = f;
}

// ---------------------------------------------------------------------------
// Kernel 2: projections via bf16 MFMA 16x16x32, epilogue stores
//   Eq = exp2(C * (qs·Wq)),  Ek = exp2(C * (ks·Wk))   (fp32).
// 512 blocks x 4 waves; block = 16 rows x 128 cols; wave w owns col-tiles 2w,2w+1.
// A-frag: A[m=lane&15][k=(lane>>4)*8+j]; C/D: col=lane&15, row=(lane>>4)*4+reg.
// ---------------------------------------------------------------------------
__global__ __launch_bounds__(256) void proj_kernel(
    const float* __restrict__ qs, const float* __restrict__ ks,
    const short* __restrict__ WqF, const short* __restrict__ WkF,
    float* __restrict__ qp, float* __restrict__ kp) {
  int blk  = blockIdx.x;                    // 0..511
  int wave = threadIdx.x >> 6;              // 0..3
  int l    = threadIdx.x & 63;
  int grow = blk * 16;
  int m    = (grow >= 4096) ? 1 : 0;
  int r0   = grow - (m ? 4096 : 0);
  const float*  A  = m ? ks : qs;
  const short8* BF = (const short8*)(m ? WkF : WqF);
  float* out = m ? kp : qp;

  float4v acc[2];
  acc[0] = (float4v){0.f, 0.f, 0.f, 0.f};
  acc[1] = (float4v){0.f, 0.f, 0.f, 0.f};

  int quad = l >> 4;
  int arow = r0 + (l & 15);
  const float* aptr = A + (size_t)arow * D_ + quad * 8;
  int t0 = wave * 2;

#pragma unroll 4
  for (int kb = 0; kb < 16; ++kb) {
    float4v a0 = *(const float4v*)(aptr + kb * 32);
    float4v a1 = *(const float4v*)(aptr + kb * 32 + 4);
    short8 af;
#pragma unroll
    for (int j = 0; j < 4; ++j) { af[j] = bf16rne(a0[j]); af[j + 4] = bf16rne(a1[j]); }
#pragma unroll
    for (int tt = 0; tt < 2; ++tt) {
      short8 bf = BF[((t0 + tt) * 16 + kb) * 64 + l];
      acc[tt] = __builtin_amdgcn_mfma_f32_16x16x32_bf16(af, bf, acc[tt], 0, 0, 0);
    }
  }

#pragma unroll
  for (int tt = 0; tt < 2; ++tt)
#pragma unroll
    for (int r = 0; r < 4; ++r) {
      int row = r0 + quad * 4 + r;
      int col = (t0 + tt) * 16 + (l & 15);
      // |proj| <~ 5 for this data => exp2 arg in [-15,15]: no overflow/underflow.
      out[(size_t)row * H_ + col] = __builtin_amdgcn_exp2f(acc[tt][r] * TANH_C);
    }
}

// ---------------------------------------------------------------------------
// Kernel 3: scores — IDENTICAL to R9 (measurement round: launched 3x to
// expose its duration as (dur_R10 - dur_R9)/2; it is idempotent).
//   out = W0 + sum_h w2_h * rcp(fma(Eq_h, Ek_h, 1)), quad-h amortized,
//   fully packed over 4 consecutive k-cols per thread.
// ---------------------------------------------------------------------------
__global__ __launch_bounds__(128, 2) void score_kernel(
    const float* __restrict__ qp, const float* __restrict__ kp,
    const float* __restrict__ w2, const float* __restrict__ W0buf,
    float* __restrict__ out) {
  __shared__ float qt[64 * 68];   // [qrow][h_local]
  __shared__ float kt[64 * 36];   // [h_local][kcol] (pad 36)
  __shared__ float wl[H_];

  int b = blockIdx.z, qtile = blockIdx.y, ktile = blockIdx.x;
  int t = threadIdx.x;                      // 0..127
  int tx = t & 7, ty = t >> 3;              // compute: cols 4tx.., rows ty+16i

  const float* qbase = qp + (size_t)(b * LQ_ + qtile * 64) * H_;
  const float* kbase = kp + (size_t)(b * LK_ + ktile * 32) * H_;

  float W0 = W0buf[0];                      // uniform scalar load

  if (t < 32) *(float4v*)&wl[t * 4] = *(const float4v*)&w2[t * 4];

  float4v acc[4];                           // per i, float4 over j
  const float4v ones = (float4v){1.f, 1.f, 1.f, 1.f};
#pragma unroll
  for (int i = 0; i < 4; ++i) acc[i] = (float4v){0.f, 0.f, 0.f, 0.f};

  int lr = t >> 4, lc = t & 15;             // load phase: row / float4-col

  for (int hc = 0; hc < 2; ++hc) {
    __syncthreads();                        // first pass also covers wl visibility
#pragma unroll
    for (int s = 0; s < 8; ++s) {           // qt: 64 rows x 16 float4 (row-major)
      int row = lr + 8 * s;
      *(float4v*)&qt[row * 68 + lc * 4] =
          *(const float4v*)&qbase[row * H_ + hc * 64 + lc * 4];
    }
#pragma unroll
    for (int s = 0; s < 4; ++s) {           // kt: transpose 32 rows x 64 h
      int row = lr + 8 * s;
      float4v g = *(const float4v*)&kbase[row * H_ + hc * 64 + lc * 4];
#pragma unroll
      for (int u = 0; u < 4; ++u) kt[(lc * 4 + u) * 36 + row] = g[u];
    }
    __syncthreads();

#pragma unroll 4
    for (int h0 = 0; h0 < 64; h0 += 4) {
      float4v kv[4];
#pragma unroll
      for (int hh = 0; hh < 4; ++hh)
        kv[hh] = *(const float4v*)&kt[(h0 + hh) * 36 + tx * 4];
      float4v w4 = *(const float4v*)&wl[hc * 64 + h0];   // uniform broadcast

#pragma unroll
      for (int i = 0; i < 4; ++i) {
        float4v qv = *(const float4v*)&qt[(ty + 16 * i) * 68 + h0];
        float4v den0 = __builtin_elementwise_fma(splat4(qv[0]), kv[0], ones);
        float4v den1 = __builtin_elementwise_fma(splat4(qv[1]), kv[1], ones);
        float4v den2 = __builtin_elementwise_fma(splat4(qv[2]), kv[2], ones);
        float4v den3 = __builtin_elementwise_fma(splat4(qv[3]), kv[3], ones);
        float4v d01 = den0 * den1;
        float4v d23 = den2 * den3;
        float4v P   = d01 * d23;
        float4v n01 = __builtin_elementwise_fma(splat4(w4[1]), den0, splat4(w4[0]) * den1);
        float4v n23 = __builtin_elementwise_fma(splat4(w4[3]), den2, splat4(w4[2]) * den3);
        float4v N   = __builtin_elementwise_fma(n01, d23, n23 * d01);
        float4v r;
        r[0] = __builtin_amdgcn_rcpf(P[0]);
        r[1] = __builtin_amdgcn_rcpf(P[1]);
        r[2] = __builtin_amdgcn_rcpf(P[2]);
        r[3] = __builtin_amdgcn_rcpf(P[3]);
        acc[i] = __builtin_elementwise_fma(N, r, acc[i]);
      }
    }
  }

  size_t ob = (size_t)(b * LQ_ + qtile * 64) * LK_ + ktile * 32;
#pragma unroll
  for (int i = 0; i < 4; ++i) {
    float4v o = acc[i] + splat4(W0);
    *(float4v*)&out[ob + (size_t)(ty + 16 * i) * LK_ + tx * 4] = o;
  }
}

// ---------------------------------------------------------------------------
extern "C" void kernel_launch(void* const* d_in, const int* in_sizes, int n_in,
                              void* d_out, int out_size, void* d_ws, size_t ws_size,
                              hipStream_t stream) {
  const float* qs = (const float*)d_in[0];
  const float* ks = (const float*)d_in[1];
  const float* Wq = (const float*)d_in[2];
  const float* Wk = (const float*)d_in[3];
  const float* wv = (const float*)d_in[4];
  float* out = (float*)d_out;

  char* ws = (char*)d_ws;
  short* WqF  = (short*)ws;                               // 128 KB
  short* WkF  = (short*)(ws + (128 << 10));               // 128 KB
  float* qp   = (float*)(ws + (256 << 10));               // 2 MB (Eq)
  float* kp   = (float*)(ws + (256 << 10) + (2 << 20));   // 2 MB (Ek)
  float* w2   = (float*)(ws + (256 << 10) + (4 << 20));   // 512 B (-2*wv)
  float* W0b  = (float*)(ws + (256 << 10) + (4 << 20) + 512);  // 4 B (sum wv)

  prep_kernel<<<64, 256, 0, stream>>>(Wq, Wk, wv, WqF, WkF, w2, W0b);
  proj_kernel<<<512, 256, 0, stream>>>(qs, ks, WqF, WkF, qp, kp);
  // MEASUREMENT: score launched 3x (idempotent; same work every call).
  // score_dur = (dur_R10 - dur_R9) / 2.
  score_kernel<<<dim3(16, 8, 8), 128, 0, stream>>>(qp, kp, w2, W0b, out);
  score_kernel<<<dim3(16, 8, 8), 128, 0, stream>>>(qp, kp, w2, W0b, out);
  score_kernel<<<dim3(16, 8, 8), 128, 0, stream>>>(qp, kp, w2, W0b, out);
}

// Round 11
// 121.015 us; speedup vs baseline: 1.3241x; 1.3241x over previous
//
#include <hip/hip_runtime.h>
#include <hip/hip_bf16.h>
#include <cstdint>

#define B_   8
#define LQ_  512
#define LK_  512
#define D_   512
#define H_   128
#define NK_  (B_ * LK_)   // 4096 total k rows

typedef __attribute__((ext_vector_type(8))) short  short8;   // 8 bf16 in 4 VGPRs
typedef __attribute__((ext_vector_type(4))) float  float4v;

// Eq = e^{2x} = exp2(C*x), C = 2*log2(e). tanh(q+k) = 1 - 2/(1 + Eq*Ek) exactly.
#define TANH_C 2.8853900817779268f

__device__ __forceinline__ short bf16rne(float x) {
  uint32_t u = __float_as_uint(x);
  return (short)((u + 0x7fffu + ((u >> 16) & 1u)) >> 16);
}

__device__ __forceinline__ float4v splat4(float x) {
  return (float4v){x, x, x, x};
}

// ---------------------------------------------------------------------------
// Kernel 1: reorder Wq/Wk (bf16) into MFMA B-fragment order, plus bake
//   w2[h] = -2*wv[h]  and  W0 = sum_h wv[h]  into ws for the score kernel.
// ---------------------------------------------------------------------------
__global__ __launch_bounds__(256) void prep_kernel(
    const float* __restrict__ Wq, const float* __restrict__ Wk,
    const float* __restrict__ wv,
    short* __restrict__ WqF, short* __restrict__ WkF,
    float* __restrict__ w2, float* __restrict__ W0buf) {
  int g = blockIdx.x * 256 + threadIdx.x;   // 0 .. 16383
  if (blockIdx.x == 0) {
    int t = threadIdx.x;
    if (t < H_) w2[t] = -2.0f * wv[t];
    if (t == H_) {
      float s = 0.f;
      for (int h = 0; h < H_; ++h) s += wv[h];
      W0buf[0] = s;
    }
  }
  int m = g >> 13;                          // 0: Wq, 1: Wk
  int r = g & 8191;                         // fragment index
  int l  = r & 63;
  int kb = (r >> 6) & 15;
  int nt = r >> 10;
  int col = nt * 16 + (l & 15);
  int k0  = kb * 32 + ((l >> 4) << 3);
  const float* W = m ? Wk : Wq;
  short8 f;
#pragma unroll
  for (int j = 0; j < 8; ++j) f[j] = bf16rne(W[(k0 + j) * H_ + col]);
  ((short8*)(m ? WkF : WqF))[r] = f;
}

// ---------------------------------------------------------------------------
// Kernel 2: projections via bf16 MFMA 16x16x32.
// q side: stores Eq row-major  qp[row][h]   (row = global q row, 0..4095)
// k side: stores Ek TRANSPOSED kpT[h][row]  (h-major, row = global k row)
//   so the score kernel can read 4 consecutive k-cols with one contiguous
//   16B global load (same-address across ty-lanes -> vmem broadcast,
//   moving the k-read off the saturated LDS pipe).
// kpT scatter: for fixed (tt,r) the 64 lanes write 16 cols x 4 rows; over
// r=0..3 each col's 16 consecutive rows fill one 64B line -> write-combines.
// ---------------------------------------------------------------------------
__global__ __launch_bounds__(256) void proj_kernel(
    const float* __restrict__ qs, const float* __restrict__ ks,
    const short* __restrict__ WqF, const short* __restrict__ WkF,
    float* __restrict__ qp, float* __restrict__ kpT) {
  int blk  = blockIdx.x;                    // 0..511
  int wave = threadIdx.x >> 6;              // 0..3
  int l    = threadIdx.x & 63;
  int grow = blk * 16;
  int m    = (grow >= 4096) ? 1 : 0;
  int r0   = grow - (m ? 4096 : 0);
  const float*  A  = m ? ks : qs;
  const short8* BF = (const short8*)(m ? WkF : WqF);

  float4v acc[2];
  acc[0] = (float4v){0.f, 0.f, 0.f, 0.f};
  acc[1] = (float4v){0.f, 0.f, 0.f, 0.f};

  int quad = l >> 4;
  int arow = r0 + (l & 15);
  const float* aptr = A + (size_t)arow * D_ + quad * 8;
  int t0 = wave * 2;

#pragma unroll 4
  for (int kb = 0; kb < 16; ++kb) {
    float4v a0 = *(const float4v*)(aptr + kb * 32);
    float4v a1 = *(const float4v*)(aptr + kb * 32 + 4);
    short8 af;
#pragma unroll
    for (int j = 0; j < 4; ++j) { af[j] = bf16rne(a0[j]); af[j + 4] = bf16rne(a1[j]); }
#pragma unroll
    for (int tt = 0; tt < 2; ++tt) {
      short8 bf = BF[((t0 + tt) * 16 + kb) * 64 + l];
      acc[tt] = __builtin_amdgcn_mfma_f32_16x16x32_bf16(af, bf, acc[tt], 0, 0, 0);
    }
  }

#pragma unroll
  for (int tt = 0; tt < 2; ++tt)
#pragma unroll
    for (int r = 0; r < 4; ++r) {
      int row = r0 + quad * 4 + r;
      int col = (t0 + tt) * 16 + (l & 15);
      // |proj| <~ 5 for this data => exp2 arg in [-15,15]: no overflow/underflow.
      float e = __builtin_amdgcn_exp2f(acc[tt][r] * TANH_C);
      if (m) kpT[(size_t)col * NK_ + row] = e;
      else   qp [(size_t)row * H_  + col] = e;
    }
}

// ---------------------------------------------------------------------------
// Kernel 3: scores.  out = W0 + sum_h w2_h * rcp(fma(Eq_h, Ek_h, 1)).
// Quad-h reciprocal amortization, fully packed over 4 consecutive k-cols
// (identical algebra to R9, which passed at absmax 0.0156).
// R11 CHANGE: k is read DIRECTLY FROM GLOBAL (kpT, h-major, L2-resident
// 2 MB) — same-address ty-lanes coalesce to 8 distinct 16B segments/instr,
// so the k-read moves to the near-idle vmem pipe. LDS keeps only q + wl:
// LDS pipe drops from 9 to 5 b128-instrs per h0-step (11.5 -> ~6.4 us),
// leaving VALU (~9.4 us) as the floor. Single staging phase (full 128-h
// q tile, LDS 33.8 KB, pad 132) and ONE barrier total.
// Block = 64q x 32k, 128 thr (thread = rows ty+16i, cols 4tx..4tx+3),
// grid 1024 = 4 blocks/CU.
// ---------------------------------------------------------------------------
__global__ __launch_bounds__(128, 2) void score_kernel(
    const float* __restrict__ qp, const float* __restrict__ kpT,
    const float* __restrict__ w2, const float* __restrict__ W0buf,
    float* __restrict__ out) {
  __shared__ float qt[64 * 132];  // [qrow][h] pad 132: conflict-free compute reads
  __shared__ float wl[H_];

  int b = blockIdx.z, qtile = blockIdx.y, ktile = blockIdx.x;
  int t = threadIdx.x;                      // 0..127
  int tx = t & 7, ty = t >> 3;              // compute: cols 4tx.., rows ty+16i

  const float* qbase = qp + (size_t)(b * LQ_ + qtile * 64) * H_;
  const float* kTb   = kpT + (size_t)(b * LK_ + ktile * 32) + tx * 4;

  float W0 = W0buf[0];                      // uniform scalar load

  if (t < 32) *(float4v*)&wl[t * 4] = *(const float4v*)&w2[t * 4];

  float4v acc[4];                           // per i, float4 over j
  const float4v ones = (float4v){1.f, 1.f, 1.f, 1.f};
#pragma unroll
  for (int i = 0; i < 4; ++i) acc[i] = (float4v){0.f, 0.f, 0.f, 0.f};

  // Stage the full 64x128 q tile (2048 float4, 16 per thread), coalesced.
#pragma unroll
  for (int s = 0; s < 16; ++s) {
    int idx = s * 128 + t;
    int row = idx >> 5, c4 = idx & 31;
    *(float4v*)&qt[row * 132 + c4 * 4] = *(const float4v*)&qbase[row * H_ + c4 * 4];
  }
  __syncthreads();

#pragma unroll 4
  for (int h0 = 0; h0 < H_; h0 += 4) {
    float4v kv[4];
#pragma unroll
    for (int hh = 0; hh < 4; ++hh)
      kv[hh] = *(const float4v*)&kTb[(size_t)(h0 + hh) * NK_];
    float4v w4 = *(const float4v*)&wl[h0];   // uniform LDS broadcast

#pragma unroll
    for (int i = 0; i < 4; ++i) {
      float4v qv = *(const float4v*)&qt[(ty + 16 * i) * 132 + h0];
      float4v den0 = __builtin_elementwise_fma(splat4(qv[0]), kv[0], ones);
      float4v den1 = __builtin_elementwise_fma(splat4(qv[1]), kv[1], ones);
      float4v den2 = __builtin_elementwise_fma(splat4(qv[2]), kv[2], ones);
      float4v den3 = __builtin_elementwise_fma(splat4(qv[3]), kv[3], ones);
      float4v d01 = den0 * den1;
      float4v d23 = den2 * den3;
      float4v P   = d01 * d23;
      float4v n01 = __builtin_elementwise_fma(splat4(w4[1]), den0, splat4(w4[0]) * den1);
      float4v n23 = __builtin_elementwise_fma(splat4(w4[3]), den2, splat4(w4[2]) * den3);
      float4v N   = __builtin_elementwise_fma(n01, d23, n23 * d01);
      float4v r;
      r[0] = __builtin_amdgcn_rcpf(P[0]);
      r[1] = __builtin_amdgcn_rcpf(P[1]);
      r[2] = __builtin_amdgcn_rcpf(P[2]);
      r[3] = __builtin_amdgcn_rcpf(P[3]);
      acc[i] = __builtin_elementwise_fma(N, r, acc[i]);
    }
  }

  size_t ob = (size_t)(b * LQ_ + qtile * 64) * LK_ + ktile * 32;
#pragma unroll
  for (int i = 0; i < 4; ++i) {
    float4v o = acc[i] + splat4(W0);
    *(float4v*)&out[ob + (size_t)(ty + 16 * i) * LK_ + tx * 4] = o;
  }
}

// ---------------------------------------------------------------------------
extern "C" void kernel_launch(void* const* d_in, const int* in_sizes, int n_in,
                              void* d_out, int out_size, void* d_ws, size_t ws_size,
                              hipStream_t stream) {
  const float* qs = (const float*)d_in[0];
  const float* ks = (const float*)d_in[1];
  const float* Wq = (const float*)d_in[2];
  const float* Wk = (const float*)d_in[3];
  const float* wv = (const float*)d_in[4];
  float* out = (float*)d_out;

  char* ws = (char*)d_ws;
  short* WqF  = (short*)ws;                               // 128 KB
  short* WkF  = (short*)(ws + (128 << 10));               // 128 KB
  float* qp   = (float*)(ws + (256 << 10));               // 2 MB (Eq, row-major)
  float* kpT  = (float*)(ws + (256 << 10) + (2 << 20));   // 2 MB (Ek, h-major)
  float* w2   = (float*)(ws + (256 << 10) + (4 << 20));   // 512 B (-2*wv)
  float* W0b  = (float*)(ws + (256 << 10) + (4 << 20) + 512);  // 4 B (sum wv)

  prep_kernel<<<64, 256, 0, stream>>>(Wq, Wk, wv, WqF, WkF, w2, W0b);
  proj_kernel<<<512, 256, 0, stream>>>(qs, ks, WqF, WkF, qp, kpT);
  score_kernel<<<dim3(16, 8, 8), 128, 0, stream>>>(qp, kpT, w2, W0b, out);
}

// Round 12
// 110.807 us; speedup vs baseline: 1.4461x; 1.0921x over previous
//
#include <hip/hip_runtime.h>
#include <hip/hip_bf16.h>
#include <cstdint>

#define B_   8
#define LQ_  512
#define LK_  512
#define D_   512
#define H_   128

typedef __attribute__((ext_vector_type(8))) short  short8;   // 8 bf16 in 4 VGPRs
typedef __attribute__((ext_vector_type(4))) float  float4v;

// Eq = e^{2x} = exp2(C*x), C = 2*log2(e). tanh(q+k) = 1 - 2/(1 + Eq*Ek) exactly.
#define TANH_C 2.8853900817779268f

__device__ __forceinline__ short bf16rne(float x) {
  uint32_t u = __float_as_uint(x);
  return (short)((u + 0x7fffu + ((u >> 16) & 1u)) >> 16);
}

__device__ __forceinline__ float4v splat4(float x) {
  return (float4v){x, x, x, x};
}

// ---------------------------------------------------------------------------
// Kernel 1: reorder Wq/Wk (bf16) into MFMA B-fragment order, plus bake
//   w2[h] = -2*wv[h]  and  W0 = sum_h wv[h]  into ws for the score kernel.
// ---------------------------------------------------------------------------
__global__ __launch_bounds__(256) void prep_kernel(
    const float* __restrict__ Wq, const float* __restrict__ Wk,
    const float* __restrict__ wv,
    short* __restrict__ WqF, short* __restrict__ WkF,
    float* __restrict__ w2, float* __restrict__ W0buf) {
  int g = blockIdx.x * 256 + threadIdx.x;   // 0 .. 16383
  if (blockIdx.x == 0) {
    int t = threadIdx.x;
    if (t < H_) w2[t] = -2.0f * wv[t];
    if (t == H_) {
      float s = 0.f;
      for (int h = 0; h < H_; ++h) s += wv[h];
      W0buf[0] = s;
    }
  }
  int m = g >> 13;                          // 0: Wq, 1: Wk
  int r = g & 8191;                         // fragment index
  int l  = r & 63;
  int kb = (r >> 6) & 15;
  int nt = r >> 10;
  int col = nt * 16 + (l & 15);
  int k0  = kb * 32 + ((l >> 4) << 3);
  const float* W = m ? Wk : Wq;
  short8 f;
#pragma unroll
  for (int j = 0; j < 8; ++j) f[j] = bf16rne(W[(k0 + j) * H_ + col]);
  ((short8*)(m ? WkF : WqF))[r] = f;
}

// ---------------------------------------------------------------------------
// Kernel 2: projections via bf16 MFMA 16x16x32, epilogue stores
//   Eq = exp2(C * (qs·Wq)),  Ek = exp2(C * (ks·Wk))   (fp32), both row-major
// (R11's h-major global k experiment REVERTED: vmem broadcast latency at
// 2 waves/SIMD cost +10 us).
// 512 blocks x 4 waves; block = 16 rows x 128 cols; wave w owns col-tiles 2w,2w+1.
// A-frag: A[m=lane&15][k=(lane>>4)*8+j]; C/D: col=lane&15, row=(lane>>4)*4+reg.
// ---------------------------------------------------------------------------
__global__ __launch_bounds__(256) void proj_kernel(
    const float* __restrict__ qs, const float* __restrict__ ks,
    const short* __restrict__ WqF, const short* __restrict__ WkF,
    float* __restrict__ qp, float* __restrict__ kp) {
  int blk  = blockIdx.x;                    // 0..511
  int wave = threadIdx.x >> 6;              // 0..3
  int l    = threadIdx.x & 63;
  int grow = blk * 16;
  int m    = (grow >= 4096) ? 1 : 0;
  int r0   = grow - (m ? 4096 : 0);
  const float*  A  = m ? ks : qs;
  const short8* BF = (const short8*)(m ? WkF : WqF);
  float* out = m ? kp : qp;

  float4v acc[2];
  acc[0] = (float4v){0.f, 0.f, 0.f, 0.f};
  acc[1] = (float4v){0.f, 0.f, 0.f, 0.f};

  int quad = l >> 4;
  int arow = r0 + (l & 15);
  const float* aptr = A + (size_t)arow * D_ + quad * 8;
  int t0 = wave * 2;

#pragma unroll 4
  for (int kb = 0; kb < 16; ++kb) {
    float4v a0 = *(const float4v*)(aptr + kb * 32);
    float4v a1 = *(const float4v*)(aptr + kb * 32 + 4);
    short8 af;
#pragma unroll
    for (int j = 0; j < 4; ++j) { af[j] = bf16rne(a0[j]); af[j + 4] = bf16rne(a1[j]); }
#pragma unroll
    for (int tt = 0; tt < 2; ++tt) {
      short8 bf = BF[((t0 + tt) * 16 + kb) * 64 + l];
      acc[tt] = __builtin_amdgcn_mfma_f32_16x16x32_bf16(af, bf, acc[tt], 0, 0, 0);
    }
  }

#pragma unroll
  for (int tt = 0; tt < 2; ++tt)
#pragma unroll
    for (int r = 0; r < 4; ++r) {
      int row = r0 + quad * 4 + r;
      int col = (t0 + tt) * 16 + (l & 15);
      // |proj| <~ 5 for this data => exp2 arg in [-15,15]: no overflow/underflow.
      out[(size_t)row * H_ + col] = __builtin_amdgcn_exp2f(acc[tt][r] * TANH_C);
    }
}

// ---------------------------------------------------------------------------
// Kernel 3: scores — R9 layout/algebra (measured 22 us in R10), plus R12's
// one change: EXPLICIT REGISTER PREFETCH. Step n+1's kv/qv/w4 ds_reads are
// issued before step n's compute, making the LDS dependency distance one
// full step (~130 VALU cyc > ~120 cyc ds_read latency) instead of ~0 —
// attacking the ~7 us stall gap between measured 22 and the
// max(VALU ~15, LDS ~11.5) overlap floor. Algebra identical to R9 (passed,
// absmax 0.0156): quad-h rcp amortization, packed over 4 consecutive k-cols.
// Block = 64q x 32k, 128 thr, grid 1024; LDS: qt[64][68] + kt-transposed
// [64h][36] + wl. All hot reads conflict-free (0 conflicts R2-R10).
// ---------------------------------------------------------------------------
__global__ __launch_bounds__(128, 2) void score_kernel(
    const float* __restrict__ qp, const float* __restrict__ kp,
    const float* __restrict__ w2, const float* __restrict__ W0buf,
    float* __restrict__ out) {
  __shared__ float qt[64 * 68];   // [qrow][h_local]
  __shared__ float kt[64 * 36];   // [h_local][kcol] (pad 36)
  __shared__ float wl[H_];

  int b = blockIdx.z, qtile = blockIdx.y, ktile = blockIdx.x;
  int t = threadIdx.x;                      // 0..127
  int tx = t & 7, ty = t >> 3;              // compute: cols 4tx.., rows ty+16i

  const float* qbase = qp + (size_t)(b * LQ_ + qtile * 64) * H_;
  const float* kbase = kp + (size_t)(b * LK_ + ktile * 32) * H_;

  float W0 = W0buf[0];                      // uniform scalar load

  if (t < 32) *(float4v*)&wl[t * 4] = *(const float4v*)&w2[t * 4];

  float4v acc[4];                           // per i, float4 over j
  const float4v ones = (float4v){1.f, 1.f, 1.f, 1.f};
#pragma unroll
  for (int i = 0; i < 4; ++i) acc[i] = (float4v){0.f, 0.f, 0.f, 0.f};

  int lr = t >> 4, lc = t & 15;             // load phase: row / float4-col

  for (int hc = 0; hc < 2; ++hc) {
    __syncthreads();                        // first pass also covers wl visibility
#pragma unroll
    for (int s = 0; s < 8; ++s) {           // qt: 64 rows x 16 float4 (row-major)
      int row = lr + 8 * s;
      *(float4v*)&qt[row * 68 + lc * 4] =
          *(const float4v*)&qbase[row * H_ + hc * 64 + lc * 4];
    }
#pragma unroll
    for (int s = 0; s < 4; ++s) {           // kt: transpose 32 rows x 64 h
      int row = lr + 8 * s;
      float4v g = *(const float4v*)&kbase[row * H_ + hc * 64 + lc * 4];
#pragma unroll
      for (int u = 0; u < 4; ++u) kt[(lc * 4 + u) * 36 + row] = g[u];
    }
    __syncthreads();

    // ---- software-pipelined inner loop: prefetch step n+1 before compute n.
    float4v kvN[4], qvN[4], w4N;
#pragma unroll
    for (int hh = 0; hh < 4; ++hh)
      kvN[hh] = *(const float4v*)&kt[hh * 36 + tx * 4];
#pragma unroll
    for (int i = 0; i < 4; ++i)
      qvN[i] = *(const float4v*)&qt[(ty + 16 * i) * 68];
    w4N = *(const float4v*)&wl[hc * 64];

#pragma unroll
    for (int h0 = 0; h0 < 64; h0 += 4) {
      float4v kv[4], qv[4], w4;
#pragma unroll
      for (int hh = 0; hh < 4; ++hh) kv[hh] = kvN[hh];
#pragma unroll
      for (int i = 0; i < 4; ++i) qv[i] = qvN[i];
      w4 = w4N;

      if (h0 + 4 < 64) {                    // issue next step's ds_reads NOW
#pragma unroll
        for (int hh = 0; hh < 4; ++hh)
          kvN[hh] = *(const float4v*)&kt[(h0 + 4 + hh) * 36 + tx * 4];
#pragma unroll
        for (int i = 0; i < 4; ++i)
          qvN[i] = *(const float4v*)&qt[(ty + 16 * i) * 68 + h0 + 4];
        w4N = *(const float4v*)&wl[hc * 64 + h0 + 4];
      }

#pragma unroll
      for (int i = 0; i < 4; ++i) {
        float4v den0 = __builtin_elementwise_fma(splat4(qv[i][0]), kv[0], ones);
        float4v den1 = __builtin_elementwise_fma(splat4(qv[i][1]), kv[1], ones);
        float4v den2 = __builtin_elementwise_fma(splat4(qv[i][2]), kv[2], ones);
        float4v den3 = __builtin_elementwise_fma(splat4(qv[i][3]), kv[3], ones);
        float4v d01 = den0 * den1;
        float4v d23 = den2 * den3;
        float4v P   = d01 * d23;
        float4v n01 = __builtin_elementwise_fma(splat4(w4[1]), den0, splat4(w4[0]) * den1);
        float4v n23 = __builtin_elementwise_fma(splat4(w4[3]), den2, splat4(w4[2]) * den3);
        float4v N   = __builtin_elementwise_fma(n01, d23, n23 * d01);
        float4v r;
        r[0] = __builtin_amdgcn_rcpf(P[0]);
        r[1] = __builtin_amdgcn_rcpf(P[1]);
        r[2] = __builtin_amdgcn_rcpf(P[2]);
        r[3] = __builtin_amdgcn_rcpf(P[3]);
        acc[i] = __builtin_elementwise_fma(N, r, acc[i]);
      }
    }
  }

  size_t ob = (size_t)(b * LQ_ + qtile * 64) * LK_ + ktile * 32;
#pragma unroll
  for (int i = 0; i < 4; ++i) {
    float4v o = acc[i] + splat4(W0);
    *(float4v*)&out[ob + (size_t)(ty + 16 * i) * LK_ + tx * 4] = o;
  }
}

// ---------------------------------------------------------------------------
extern "C" void kernel_launch(void* const* d_in, const int* in_sizes, int n_in,
                              void* d_out, int out_size, void* d_ws, size_t ws_size,
                              hipStream_t stream) {
  const float* qs = (const float*)d_in[0];
  const float* ks = (const float*)d_in[1];
  const float* Wq = (const float*)d_in[2];
  const float* Wk = (const float*)d_in[3];
  const float* wv = (const float*)d_in[4];
  float* out = (float*)d_out;

  char* ws = (char*)d_ws;
  short* WqF  = (short*)ws;                               // 128 KB
  short* WkF  = (short*)(ws + (128 << 10));               // 128 KB
  float* qp   = (float*)(ws + (256 << 10));               // 2 MB (Eq, row-major)
  float* kp   = (float*)(ws + (256 << 10) + (2 << 20));   // 2 MB (Ek, row-major)
  float* w2   = (float*)(ws + (256 << 10) + (4 << 20));   // 512 B (-2*wv)
  float* W0b  = (float*)(ws + (256 << 10) + (4 << 20) + 512);  // 4 B (sum wv)

  prep_kernel<<<64, 256, 0, stream>>>(Wq, Wk, wv, WqF, WkF, w2, W0b);
  proj_kernel<<<512, 256, 0, stream>>>(qs, ks, WqF, WkF, qp, kp);
  score_kernel<<<dim3(16, 8, 8), 128, 0, stream>>>(qp, kp, w2, W0b, out);
}